// Round 4
// baseline (173.622 us; speedup 1.0000x reference)
//
#include <hip/hip_runtime.h>
#include <hip/hip_bf16.h>

#define NN   4096   // nodes
#define DD   512    // in_dim (= 8 heads * 64)
#define KH   8      // heads
#define RR   64     // sub_dim
#define CAP  128    // max neighbors kept (deg ~ 42 +- 6.4; 128 is 13 sigma)

typedef unsigned short u16;
typedef unsigned int   u32;
typedef __attribute__((ext_vector_type(8))) short short8;  // 8 bf16 (MFMA A/B frag)
typedef __attribute__((ext_vector_type(4))) float f32x4;   // MFMA C/D frag

__device__ __forceinline__ float bflo(u32 v){ union{u32 i; float f;} c; c.i = v << 16;        return c.f; }
__device__ __forceinline__ float bfhi(u32 v){ union{u32 i; float f;} c; c.i = v & 0xFFFF0000u; return c.f; }
__device__ __forceinline__ u16 f2bf(float f){ __hip_bfloat16 h = __float2bfloat16(f); return *reinterpret_cast<u16*>(&h); }

// ---------------------------------------------------------------------------
// P0: streaming prep + orth partials. b<4096: mask scan -> nlist/cnt.
// b<6144: H->Hb bf16. b<6208: U -> Bt1/Bt2 transposes. b>=6208: orth-loss
// pair-strip partial -> lossP[b-6208] (plain store, no atomics; VALU-heavy
// work overlaps the BW-bound streaming blocks). outgemm sums lossP later
// (stream order => visible). LDS shapes overlaid via union.
// ---------------------------------------------------------------------------
__global__ __launch_bounds__(256) void prep_scan(const float* __restrict__ H, const float* __restrict__ U,
                                                 const float* __restrict__ adj,
                                                 u16* __restrict__ Hb, u16* __restrict__ Bt1,
                                                 u16* __restrict__ Bt2,
                                                 int* __restrict__ nlist, int* __restrict__ cnt,
                                                 float* __restrict__ lossP) {
    union SH {
        struct { float tile[64][65]; int list[CAP]; int cntS; } p;
        struct { float UkT[64][20]; float UlT[64][68]; } o;
    };
    __shared__ SH sh;
    __shared__ float red4[4];
    const int b = blockIdx.x, t = threadIdx.x;
    if (b < 4096) {
        // ---- mask scan ----
        const int i = b;
        if (t == 0) sh.p.cntS = 0;
        __syncthreads();
        const float* arow = adj + (size_t)i * NN;
        #pragma unroll
        for (int qq = 0; qq < 4; qq++) {
            int j = (qq * 256 + t) * 4;
            float4 mv = *(const float4*)(arow + j);
            if (mv.x != 0.f) { int p = atomicAdd(&sh.p.cntS, 1); if (p < CAP) sh.p.list[p] = j;     }
            if (mv.y != 0.f) { int p = atomicAdd(&sh.p.cntS, 1); if (p < CAP) sh.p.list[p] = j + 1; }
            if (mv.z != 0.f) { int p = atomicAdd(&sh.p.cntS, 1); if (p < CAP) sh.p.list[p] = j + 2; }
            if (mv.w != 0.f) { int p = atomicAdd(&sh.p.cntS, 1); if (p < CAP) sh.p.list[p] = j + 3; }
        }
        __syncthreads();
        const int n = min(sh.p.cntS, CAP);
        if (t < n) nlist[(size_t)i * CAP + t] = sh.p.list[t];
        if (t == 0) cnt[i] = n;
        return;
    }
    if (b < 6144) {
        // ---- H (f32) -> Hb (bf16) ----
        size_t id = (size_t)(b - 4096) * 256 + t;
        float4 v = *(const float4*)(H + id * 4);
        ushort4 o; o.x = f2bf(v.x); o.y = f2bf(v.y); o.z = f2bf(v.z); o.w = f2bf(v.w);
        *(ushort4*)(Hb + id * 4) = o;
        return;
    }
    if (b < 6208) {
        // ---- U -> Bt1 [k*64+r][d], Bt2 [d][k*64+r] (bf16) ----
        const int b2 = b - 6144;
        const int k = b2 >> 3, d0 = (b2 & 7) * 64;
        #pragma unroll
        for (int s = 0; s < 4; s++) {
            int u = t + 256 * s;               // 0..1023
            int dd = u >> 4, rq = u & 15;
            float4 v = *(const float4*)(U + ((size_t)(k * DD + d0 + dd)) * RR + rq * 4);
            sh.p.tile[dd][rq * 4 + 0] = v.x; sh.p.tile[dd][rq * 4 + 1] = v.y;
            sh.p.tile[dd][rq * 4 + 2] = v.z; sh.p.tile[dd][rq * 4 + 3] = v.w;
        }
        __syncthreads();
        {   int r = t >> 2;
            #pragma unroll
            for (int ii = 0; ii < 16; ii++) {
                int dd = (t & 3) * 16 + ii;
                Bt1[(size_t)(k * RR + r) * DD + d0 + dd] = f2bf(sh.p.tile[dd][r]);
            }
        }
        {   int dd = t >> 2, rb = (t & 3) * 16;
            #pragma unroll
            for (int ii = 0; ii < 16; ii++) {
                Bt2[(size_t)(d0 + dd) * DD + k * RR + rb + ii] = f2bf(sh.p.tile[dd][rb + ii]);
            }
        }
        return;
    }
    // ---- orth partial: ob in [0,112) = (pair k<l) x 4 r-strips ----
    const int ob = b - 6208;
    const int pb = ob >> 2, strip = ob & 3;
    int idx = pb, k = 0, lh = 1;
    #pragma unroll
    for (int kk = 0; kk < 8; kk++) {
        int c = 7 - kk;
        if (idx < c) { k = kk; lh = kk + 1 + idx; break; }
        idx -= c;
    }
    const int r = t & 15;
    const int s0 = (t >> 4) * 4;
    const int r0g = strip * 16;
    const float* Uk = U + (size_t)k  * DD * RR;
    const float* Ul = U + (size_t)lh * DD * RR;
    float a0 = 0.f, a1 = 0.f, a2 = 0.f, a3 = 0.f;
    for (int dc = 0; dc < DD; dc += 64) {
        {   int dd = t >> 2, rq = t & 3;
            *(float4*)&sh.o.UkT[dd][rq * 4] = *(const float4*)(Uk + (size_t)(dc + dd) * RR + r0g + rq * 4);
        }
        #pragma unroll
        for (int s = 0; s < 4; s++) {
            int u = t + 256 * s;
            int dd = u >> 4, sq = u & 15;
            *(float4*)&sh.o.UlT[dd][sq * 4] = *(const float4*)(Ul + (size_t)(dc + dd) * RR + sq * 4);
        }
        __syncthreads();
        #pragma unroll 4
        for (int dd = 0; dd < 64; dd++) {
            float a = sh.o.UkT[dd][r];
            float4 bv = *(const float4*)&sh.o.UlT[dd][s0];
            a0 += a * bv.x; a1 += a * bv.y; a2 += a * bv.z; a3 += a * bv.w;
        }
        __syncthreads();
    }
    float v = a0 * a0 + a1 * a1 + a2 * a2 + a3 * a3;
    #pragma unroll
    for (int off = 32; off; off >>= 1) v += __shfl_down(v, off, 64);
    if ((t & 63) == 0) red4[t >> 6] = v;
    __syncthreads();
    if (t == 0) lossP[ob] = red4[0] + red4[1] + red4[2] + red4[3];
}

// ---------------------------------------------------------------------------
// K1: Zb[n][c=k*64+r] = Hb[n][:] . Bt1[c][:]  (bf16 MFMA) 64x64 tile, BK=64.
// ---------------------------------------------------------------------------
__global__ __launch_bounds__(256) void zgemm_mfma(const u16* __restrict__ Hb, const u16* __restrict__ Bt1,
                                                  u16* __restrict__ Zb) {
    __shared__ short As[64][72];   // 144 B rows, 16B-aligned
    __shared__ short Bs[64][72];
    const int t = threadIdx.x;
    const int i0 = blockIdx.x * 64, n0 = blockIdx.y * 64;
    const int w = t >> 6, lane = t & 63;
    const int lm = lane & 15, lg = lane >> 4;
    f32x4 acc[4] = {};
    for (int kc = 0; kc < DD; kc += 64) {
        #pragma unroll
        for (int s = 0; s < 2; s++) {
            int c = t + 256 * s; int row = c >> 3, g = c & 7;
            *(short8*)&As[row][g * 8] = *(const short8*)(Hb  + (size_t)(i0 + row) * DD + kc + g * 8);
            *(short8*)&Bs[row][g * 8] = *(const short8*)(Bt1 + (size_t)(n0 + row) * DD + kc + g * 8);
        }
        __syncthreads();
        #pragma unroll
        for (int ks = 0; ks < 64; ks += 32) {
            short8 af = *(const short8*)&As[w * 16 + lm][ks + lg * 8];
            #pragma unroll
            for (int b = 0; b < 4; b++) {
                short8 bfr = *(const short8*)&Bs[b * 16 + lm][ks + lg * 8];
                acc[b] = __builtin_amdgcn_mfma_f32_16x16x32_bf16(af, bfr, acc[b], 0, 0, 0);
            }
        }
        __syncthreads();
    }
    // C/D: col = lane&15, row = (lane>>4)*4 + reg  [m89-verified]
    #pragma unroll
    for (int b = 0; b < 4; b++)
        #pragma unroll
        for (int q = 0; q < 4; q++) {
            int row = i0 + w * 16 + lg * 4 + q;
            int col = n0 + b * 16 + lm;
            Zb[(size_t)row * DD + col] = f2bf(acc[b][q]);
        }
}

// ---------------------------------------------------------------------------
// K2 (attn11): sparse attention, linear softmax (no max-sub: z ~ N(0,1) per
// comp, s = z_i.z_j/8 <= ~15 -> exp <= 3e6, l <= 4e8, f32-safe; ratios
// identical; invalid slots select e=0).
// New decomposition: wave w handles neighbor slots {w, w+8, w+16, ...} for
// ALL 8 heads at once. Slot index is wave-uniform -> each per-neighbor load
// is ONE contiguous 1 KB row (uniform base + lane*16B), perfectly coalesced.
// Lane owns dims [lane*8, lane*8+8): 8-lane group (lane>>3) = head. Dot =
// 8 FMA + shfl_xor(1,2,4) within the group; aggregation in 8 regs/lane,
// already in output layout. Neighbor indices staged ONCE to LDS (kills the
// in-loop index->row global latency chain); row data prefetched depth-2.
// End: per-wave acc rows + per-(wave,head) l partials to LDS, one barrier,
// 512 threads reduce 8 ways and store. VGPR ~45 (under the 64 cliff ->
// 32 waves/CU); LDS ~17 KB (under the 40 KB 4-block bound).
// ---------------------------------------------------------------------------
__global__ __launch_bounds__(512) void attn11(const u16* __restrict__ Zb, const int* __restrict__ nlist,
                                              const int* __restrict__ cnt, u16* __restrict__ Zaggb) {
    const int i = blockIdx.x, t = threadIdx.x;
    const int w = t >> 6, lane = t & 63;
    __shared__ int   nbrS[CAP];
    __shared__ float red[KH][DD];       // 16 KB: [wave][dim] partial aggregates
    __shared__ float lS[KH][KH + 1];    // [wave][head] partial denominators
    const int ci = cnt[i];              // >= 1 (self-loop), <= CAP
    // stage clamped neighbor list: nbrS[s] valid for ANY s < CAP
    if (t < CAP) nbrS[t] = nlist[(size_t)i * CAP + min(t, ci - 1)];
    __syncthreads();

    // own z: lane's 8 dims (16 B, coalesced 1 KB per wave, L1-hot across waves)
    float a[8];
    {
        uint4 av = *(const uint4*)(Zb + (size_t)i * DD + lane * 8);
        a[0] = bflo(av.x); a[1] = bfhi(av.x); a[2] = bflo(av.y); a[3] = bfhi(av.y);
        a[4] = bflo(av.z); a[5] = bfhi(av.z); a[6] = bflo(av.w); a[7] = bfhi(av.w);
    }

    float l = 0.f;
    float acc[8] = {};
    const int nIt = (ci + 7) >> 3;      // iterations (uniform across waves)

    // depth-2 data prefetch (indices are LDS reads, cheap)
    uint4 b0 = *(const uint4*)(Zb + (size_t)nbrS[w] * DD + lane * 8);
    uint4 b1 = *(const uint4*)(Zb + (size_t)nbrS[min(w + 8, CAP - 1)] * DD + lane * 8);

    #define PROCESS(c, val)                                                        \
    {   float zf[8];                                                               \
        zf[0] = bflo(c.x); zf[1] = bfhi(c.x); zf[2] = bflo(c.y); zf[3] = bfhi(c.y);\
        zf[4] = bflo(c.z); zf[5] = bfhi(c.z); zf[6] = bflo(c.w); zf[7] = bfhi(c.w);\
        float s = zf[0]*a[0] + zf[1]*a[1] + zf[2]*a[2] + zf[3]*a[3]                \
                + zf[4]*a[4] + zf[5]*a[5] + zf[6]*a[6] + zf[7]*a[7];               \
        s += __shfl_xor(s, 1); s += __shfl_xor(s, 2); s += __shfl_xor(s, 4);       \
        const float e = (val) ? __expf(s * 0.125f) : 0.f;                          \
        l += e;                                                                    \
        _Pragma("unroll")                                                          \
        for (int d = 0; d < 8; d++) acc[d] += e * zf[d];                           \
    }

    for (int tt = 0; tt < nIt; tt += 2) {
        {   // even iter: consume b0, prefetch tt+2
            const uint4 c = b0;
            const int pf = min(w + 8 * (tt + 2), CAP - 1);
            b0 = *(const uint4*)(Zb + (size_t)nbrS[pf] * DD + lane * 8);
            const bool val = (w + 8 * tt) < ci;
            PROCESS(c, val);
        }
        if (tt + 1 < nIt) {  // odd iter: consume b1, prefetch tt+3
            const uint4 c = b1;
            const int pf = min(w + 8 * (tt + 3), CAP - 1);
            b1 = *(const uint4*)(Zb + (size_t)nbrS[pf] * DD + lane * 8);
            const bool val = (w + 8 * (tt + 1)) < ci;
            PROCESS(c, val);
        }
    }
    #undef PROCESS

    // publish per-wave partials (linear 2 KB row per wave: conflict-free)
    *(float4*)&red[w][lane * 8]     = make_float4(acc[0], acc[1], acc[2], acc[3]);
    *(float4*)&red[w][lane * 8 + 4] = make_float4(acc[4], acc[5], acc[6], acc[7]);
    if ((lane & 7) == 0) lS[w][lane >> 3] = l;   // group leader: head lane>>3
    __syncthreads();

    // final reduce: thread t = dim d; head k = d>>6 (wave-uniform -> broadcast)
    const int d = t, k = d >> 6;
    float ls = 0.f, sum = 0.f;
    #pragma unroll
    for (int ww = 0; ww < KH; ww++) { ls += lS[ww][k]; sum += red[ww][d]; }
    Zaggb[(size_t)i * DD + d] = f2bf(sum / ls);
}

// ---------------------------------------------------------------------------
// K3: out = relu(H + 0.5 * (Zaggb . Bt2^T) - thr), f32 out. 64x64, BK=64.
// Block (0,0) additionally reduces the 112 orth partials -> out[NN*DD]
// (prep wrote lossP; stream order makes it visible here).
// ---------------------------------------------------------------------------
__global__ __launch_bounds__(256) void outgemm_mfma(const u16* __restrict__ Ab, const u16* __restrict__ Btb,
                                                    const float* __restrict__ H, const float* __restrict__ thr,
                                                    const float* __restrict__ lossP,
                                                    float* __restrict__ out) {
    __shared__ short As[64][72];
    __shared__ short Bs[64][72];
    const int t = threadIdx.x;
    const int i0 = blockIdx.x * 64, n0 = blockIdx.y * 64;
    if (i0 == 0 && n0 == 0 && t < 64) {
        float v = lossP[t] + ((t + 64 < 112) ? lossP[t + 64] : 0.f);
        #pragma unroll
        for (int off = 32; off; off >>= 1) v += __shfl_down(v, off, 64);
        if (t == 0) out[(size_t)NN * DD] = v;
    }
    const int w = t >> 6, lane = t & 63;
    const int lm = lane & 15, lg = lane >> 4;
    f32x4 acc[4] = {};
    for (int kc = 0; kc < DD; kc += 64) {
        #pragma unroll
        for (int s = 0; s < 2; s++) {
            int c = t + 256 * s; int row = c >> 3, g = c & 7;
            *(short8*)&As[row][g * 8] = *(const short8*)(Ab  + (size_t)(i0 + row) * DD + kc + g * 8);
            *(short8*)&Bs[row][g * 8] = *(const short8*)(Btb + (size_t)(n0 + row) * DD + kc + g * 8);
        }
        __syncthreads();
        #pragma unroll
        for (int ks = 0; ks < 64; ks += 32) {
            short8 af = *(const short8*)&As[w * 16 + lm][ks + lg * 8];
            #pragma unroll
            for (int b = 0; b < 4; b++) {
                short8 bfr = *(const short8*)&Bs[b * 16 + lm][ks + lg * 8];
                acc[b] = __builtin_amdgcn_mfma_f32_16x16x32_bf16(af, bfr, acc[b], 0, 0, 0);
            }
        }
        __syncthreads();
    }
    #pragma unroll
    for (int b = 0; b < 4; b++) {
        const int col = n0 + b * 16 + lm;
        const float th = thr[col];
        #pragma unroll
        for (int q = 0; q < 4; q++) {
            int row = i0 + w * 16 + lg * 4 + q;
            float h = H[(size_t)row * DD + col];
            out[(size_t)row * DD + col] = fmaxf(h + 0.5f * acc[b][q] - th, 0.f);
        }
    }
}

// ---------------------------------------------------------------------------
extern "C" void kernel_launch(void* const* d_in, const int* in_sizes, int n_in,
                              void* d_out, int out_size, void* d_ws, size_t ws_size,
                              hipStream_t stream) {
    const float* H   = (const float*)d_in[0];
    const float* adj = (const float*)d_in[1];
    const float* U   = (const float*)d_in[2];
    const float* thr = (const float*)d_in[3];
    float* out = (float*)d_out;

    char* ws = (char*)d_ws;
    float* lossP = (float*)ws;                                         // 112 floats (448 B)
    u16*   Hb    = (u16*)(ws + 1024);                                  // 4 MB
    u16*   Zb    = (u16*)(ws + 1024 + 4u * 1024 * 1024);               // 4 MB
    u16*   Zaggb = (u16*)(ws + 1024 + 8u * 1024 * 1024);               // 4 MB
    u16*   Bt1   = (u16*)(ws + 1024 + 12u * 1024 * 1024);              // 512 KB
    u16*   Bt2   = (u16*)(ws + 1024 + 12u * 1024 * 1024 + 512u * 1024);// 512 KB
    int*   nlist = (int*)(ws + 1024 + 13u * 1024 * 1024);              // 2 MB
    int*   cnt   = (int*)(ws + 1024 + 15u * 1024 * 1024 + 512u * 1024);// 16 KB

    prep_scan<<<6320, 256, 0, stream>>>(H, U, adj, Hb, Bt1, Bt2, nlist, cnt, lossP);
    zgemm_mfma<<<dim3(64, 8), 256, 0, stream>>>(Hb, Bt1, Zb);
    attn11<<<NN, 512, 0, stream>>>(Zb, nlist, cnt, Zaggb);
    outgemm_mfma<<<dim3(64, 8), 256, 0, stream>>>(Zaggb, Bt2, H, thr, lossP, out);
}

// Round 5
// 157.071 us; speedup vs baseline: 1.1054x; 1.1054x over previous
//
#include <hip/hip_runtime.h>
#include <hip/hip_bf16.h>

#define NN   4096   // nodes
#define DD   512    // in_dim (= 8 heads * 64)
#define KH   8      // heads
#define RR   64     // sub_dim
#define CAP  128    // max neighbors kept (deg ~ 42 +- 6.4; 128 is 13 sigma)

typedef unsigned short u16;
typedef unsigned int   u32;
typedef unsigned long long u64;
typedef __attribute__((ext_vector_type(8))) short short8;  // 8 bf16 (MFMA A/B frag)
typedef __attribute__((ext_vector_type(4))) float f32x4;   // MFMA C/D frag

__device__ __forceinline__ float bflo(u32 v){ union{u32 i; float f;} c; c.i = v << 16;        return c.f; }
__device__ __forceinline__ float bfhi(u32 v){ union{u32 i; float f;} c; c.i = v & 0xFFFF0000u; return c.f; }
__device__ __forceinline__ u16 f2bf(float f){ __hip_bfloat16 h = __float2bfloat16(f); return *reinterpret_cast<u16*>(&h); }

// ---------------------------------------------------------------------------
// P0 layout (orth FIRST so its serial latency hides under streaming):
//   b <  112: orth-loss partial (32-row LDS chunks, 11.3 KB <= tile size)
//   b <  176: U -> Bt1/Bt2 transposes (tile[64][65], 16.6 KB)
//   b < 1200: adjacency mask scan, ONE WAVE PER ROW via ballot/popc prefix
//             compaction — no LDS, no atomics, 8 loads in flight per lane.
//   b < 3248: H (f32) -> Hb (bf16), BW-bound streaming.
// Static LDS = max(16.6, 11.3) KB -> 8 blocks/CU for the scan (wave cap),
// fixing round-4's regression (23 KB union -> 6 blocks/CU on a latency-
// bound phase).
// ---------------------------------------------------------------------------
__global__ __launch_bounds__(256) void prep_scan(const float* __restrict__ H, const float* __restrict__ U,
                                                 const float* __restrict__ adj,
                                                 u16* __restrict__ Hb, u16* __restrict__ Bt1,
                                                 u16* __restrict__ Bt2,
                                                 int* __restrict__ nlist, int* __restrict__ cnt,
                                                 float* __restrict__ lossP) {
    union SH {
        float tile[64][65];                               // U-transpose
        struct { float UkT[32][20]; float UlT[32][68]; } o; // orth (11.3 KB)
    };
    __shared__ SH sh;
    __shared__ float red4[4];
    const int b = blockIdx.x, t = threadIdx.x;

    if (b < 112) {
        // ---- orth partial: ob = (pair k<l) x 4 r-strips, 32-row dc chunks ----
        const int ob = b;
        const int pb = ob >> 2, strip = ob & 3;
        int idx = pb, k = 0, lh = 1;
        #pragma unroll
        for (int kk = 0; kk < 8; kk++) {
            int c = 7 - kk;
            if (idx < c) { k = kk; lh = kk + 1 + idx; break; }
            idx -= c;
        }
        const int r = t & 15;
        const int s0 = (t >> 4) * 4;
        const int r0g = strip * 16;
        const float* Uk = U + (size_t)k  * DD * RR;
        const float* Ul = U + (size_t)lh * DD * RR;
        float a0 = 0.f, a1 = 0.f, a2 = 0.f, a3 = 0.f;
        for (int dc = 0; dc < DD; dc += 32) {
            if (t < 128) {                       // UkT: 32 rows x 16 r-cols
                int dd = t >> 2, rq = t & 3;
                *(float4*)&sh.o.UkT[dd][rq * 4] = *(const float4*)(Uk + (size_t)(dc + dd) * RR + r0g + rq * 4);
            }
            #pragma unroll
            for (int s = 0; s < 2; s++) {        // UlT: 32 rows x 64 s-cols
                int u = t + 256 * s;
                int dd = u >> 4, sq = u & 15;
                *(float4*)&sh.o.UlT[dd][sq * 4] = *(const float4*)(Ul + (size_t)(dc + dd) * RR + sq * 4);
            }
            __syncthreads();
            #pragma unroll 4
            for (int dd = 0; dd < 32; dd++) {
                float a = sh.o.UkT[dd][r];
                float4 bv = *(const float4*)&sh.o.UlT[dd][s0];
                a0 += a * bv.x; a1 += a * bv.y; a2 += a * bv.z; a3 += a * bv.w;
            }
            __syncthreads();
        }
        float v = a0 * a0 + a1 * a1 + a2 * a2 + a3 * a3;
        #pragma unroll
        for (int off = 32; off; off >>= 1) v += __shfl_down(v, off, 64);
        if ((t & 63) == 0) red4[t >> 6] = v;
        __syncthreads();
        if (t == 0) lossP[ob] = red4[0] + red4[1] + red4[2] + red4[3];
        return;
    }
    if (b < 176) {
        // ---- U -> Bt1 [k*64+r][d], Bt2 [d][k*64+r] (bf16) ----
        const int b2 = b - 112;
        const int k = b2 >> 3, d0 = (b2 & 7) * 64;
        #pragma unroll
        for (int s = 0; s < 4; s++) {
            int u = t + 256 * s;               // 0..1023
            int dd = u >> 4, rq = u & 15;
            float4 v = *(const float4*)(U + ((size_t)(k * DD + d0 + dd)) * RR + rq * 4);
            sh.tile[dd][rq * 4 + 0] = v.x; sh.tile[dd][rq * 4 + 1] = v.y;
            sh.tile[dd][rq * 4 + 2] = v.z; sh.tile[dd][rq * 4 + 3] = v.w;
        }
        __syncthreads();
        {   int r = t >> 2;
            #pragma unroll
            for (int ii = 0; ii < 16; ii++) {
                int dd = (t & 3) * 16 + ii;
                Bt1[(size_t)(k * RR + r) * DD + d0 + dd] = f2bf(sh.tile[dd][r]);
            }
        }
        {   int dd = t >> 2, rb = (t & 3) * 16;
            #pragma unroll
            for (int ii = 0; ii < 16; ii++) {
                Bt2[(size_t)(d0 + dd) * DD + k * RR + rb + ii] = f2bf(sh.tile[dd][rb + ii]);
            }
        }
        return;
    }
    if (b < 1200) {
        // ---- mask scan: wave per row, ballot/popc prefix compaction ----
        const int row = (b - 176) * 4 + (t >> 6);
        const int lane = t & 63;
        const float* arow = adj + (size_t)row * NN;
        int* ndst = nlist + (size_t)row * CAP;
        const u64 lt = (1ull << lane) - 1;
        int base = 0;
        #pragma unroll
        for (int h = 0; h < 2; h++) {
            float4 mv[8];
            #pragma unroll
            for (int c = 0; c < 8; c++)
                mv[c] = *(const float4*)(arow + (h * 8 + c) * 256 + lane * 4);
            #pragma unroll
            for (int c = 0; c < 8; c++) {
                const int j = (h * 8 + c) * 256 + lane * 4;
                const u64 bx = __ballot(mv[c].x != 0.f);
                const u64 by = __ballot(mv[c].y != 0.f);
                const u64 bz = __ballot(mv[c].z != 0.f);
                const u64 bw = __ballot(mv[c].w != 0.f);
                const int nx = __popcll(bx), ny = __popcll(by), nz = __popcll(bz);
                if (mv[c].x != 0.f) { int p = base + __popcll(bx & lt);                if (p < CAP) ndst[p] = j;     }
                if (mv[c].y != 0.f) { int p = base + nx + __popcll(by & lt);           if (p < CAP) ndst[p] = j + 1; }
                if (mv[c].z != 0.f) { int p = base + nx + ny + __popcll(bz & lt);      if (p < CAP) ndst[p] = j + 2; }
                if (mv[c].w != 0.f) { int p = base + nx + ny + nz + __popcll(bw & lt); if (p < CAP) ndst[p] = j + 3; }
                base += nx + ny + nz + __popcll(bw);
            }
        }
        if (lane == 0) cnt[row] = min(base, CAP);
        return;
    }
    // ---- H (f32) -> Hb (bf16) ----
    size_t id = (size_t)(b - 1200) * 256 + t;
    float4 v = *(const float4*)(H + id * 4);
    ushort4 o; o.x = f2bf(v.x); o.y = f2bf(v.y); o.z = f2bf(v.z); o.w = f2bf(v.w);
    *(ushort4*)(Hb + id * 4) = o;
}

// ---------------------------------------------------------------------------
// K1: Zb[n][c=k*64+r] = Hb[n][:] . Bt1[c][:]  (bf16 MFMA) 64x64 tile, BK=64.
// ---------------------------------------------------------------------------
__global__ __launch_bounds__(256) void zgemm_mfma(const u16* __restrict__ Hb, const u16* __restrict__ Bt1,
                                                  u16* __restrict__ Zb) {
    __shared__ short As[64][72];   // 144 B rows, 16B-aligned
    __shared__ short Bs[64][72];
    const int t = threadIdx.x;
    const int i0 = blockIdx.x * 64, n0 = blockIdx.y * 64;
    const int w = t >> 6, lane = t & 63;
    const int lm = lane & 15, lg = lane >> 4;
    f32x4 acc[4] = {};
    for (int kc = 0; kc < DD; kc += 64) {
        #pragma unroll
        for (int s = 0; s < 2; s++) {
            int c = t + 256 * s; int row = c >> 3, g = c & 7;
            *(short8*)&As[row][g * 8] = *(const short8*)(Hb  + (size_t)(i0 + row) * DD + kc + g * 8);
            *(short8*)&Bs[row][g * 8] = *(const short8*)(Bt1 + (size_t)(n0 + row) * DD + kc + g * 8);
        }
        __syncthreads();
        #pragma unroll
        for (int ks = 0; ks < 64; ks += 32) {
            short8 af = *(const short8*)&As[w * 16 + lm][ks + lg * 8];
            #pragma unroll
            for (int b = 0; b < 4; b++) {
                short8 bfr = *(const short8*)&Bs[b * 16 + lm][ks + lg * 8];
                acc[b] = __builtin_amdgcn_mfma_f32_16x16x32_bf16(af, bfr, acc[b], 0, 0, 0);
            }
        }
        __syncthreads();
    }
    // C/D: col = lane&15, row = (lane>>4)*4 + reg  [m89-verified]
    #pragma unroll
    for (int b = 0; b < 4; b++)
        #pragma unroll
        for (int q = 0; q < 4; q++) {
            int row = i0 + w * 16 + lg * 4 + q;
            int col = n0 + b * 16 + lm;
            Zb[(size_t)row * DD + col] = f2bf(acc[b][q]);
        }
}

// ---------------------------------------------------------------------------
// K2 (attn11): sparse attention, linear softmax (no max-sub: z ~ N(0,1) per
// comp, s = z_i.z_j/8 <= ~15 -> exp <= 3e6, l <= 4e8, f32-safe; ratios
// identical; invalid slots select e=0).
// Wave w handles neighbor slots {w, w+8, ...} for ALL 8 heads: slot index is
// wave-uniform -> each per-neighbor load is ONE contiguous 1 KB row. Lane
// owns dims [lane*8, lane*8+8): 8-lane group = head. Dot = 8 FMA +
// shfl_xor(1,2,4); aggregation in 8 regs/lane, already in output layout.
// Indices staged once to LDS; data prefetched depth-2. One barrier at end.
// ---------------------------------------------------------------------------
__global__ __launch_bounds__(512) void attn11(const u16* __restrict__ Zb, const int* __restrict__ nlist,
                                              const int* __restrict__ cnt, u16* __restrict__ Zaggb) {
    const int i = blockIdx.x, t = threadIdx.x;
    const int w = t >> 6, lane = t & 63;
    __shared__ int   nbrS[CAP];
    __shared__ float red[KH][DD];       // 16 KB: [wave][dim] partial aggregates
    __shared__ float lS[KH][KH + 1];    // [wave][head] partial denominators
    const int ci = cnt[i];              // >= 1 (self-loop), <= CAP
    if (t < CAP) nbrS[t] = nlist[(size_t)i * CAP + min(t, ci - 1)];
    __syncthreads();

    float a[8];
    {
        uint4 av = *(const uint4*)(Zb + (size_t)i * DD + lane * 8);
        a[0] = bflo(av.x); a[1] = bfhi(av.x); a[2] = bflo(av.y); a[3] = bfhi(av.y);
        a[4] = bflo(av.z); a[5] = bfhi(av.z); a[6] = bflo(av.w); a[7] = bfhi(av.w);
    }

    float l = 0.f;
    float acc[8] = {};
    const int nIt = (ci + 7) >> 3;

    uint4 b0 = *(const uint4*)(Zb + (size_t)nbrS[w] * DD + lane * 8);
    uint4 b1 = *(const uint4*)(Zb + (size_t)nbrS[min(w + 8, CAP - 1)] * DD + lane * 8);

    #define PROCESS(c, val)                                                        \
    {   float zf[8];                                                               \
        zf[0] = bflo(c.x); zf[1] = bfhi(c.x); zf[2] = bflo(c.y); zf[3] = bfhi(c.y);\
        zf[4] = bflo(c.z); zf[5] = bfhi(c.z); zf[6] = bflo(c.w); zf[7] = bfhi(c.w);\
        float s = zf[0]*a[0] + zf[1]*a[1] + zf[2]*a[2] + zf[3]*a[3]                \
                + zf[4]*a[4] + zf[5]*a[5] + zf[6]*a[6] + zf[7]*a[7];               \
        s += __shfl_xor(s, 1); s += __shfl_xor(s, 2); s += __shfl_xor(s, 4);       \
        const float e = (val) ? __expf(s * 0.125f) : 0.f;                          \
        l += e;                                                                    \
        _Pragma("unroll")                                                          \
        for (int d = 0; d < 8; d++) acc[d] += e * zf[d];                           \
    }

    for (int tt = 0; tt < nIt; tt += 2) {
        {   const uint4 c = b0;
            const int pf = min(w + 8 * (tt + 2), CAP - 1);
            b0 = *(const uint4*)(Zb + (size_t)nbrS[pf] * DD + lane * 8);
            const bool val = (w + 8 * tt) < ci;
            PROCESS(c, val);
        }
        if (tt + 1 < nIt) {
            const uint4 c = b1;
            const int pf = min(w + 8 * (tt + 3), CAP - 1);
            b1 = *(const uint4*)(Zb + (size_t)nbrS[pf] * DD + lane * 8);
            const bool val = (w + 8 * (tt + 1)) < ci;
            PROCESS(c, val);
        }
    }
    #undef PROCESS

    *(float4*)&red[w][lane * 8]     = make_float4(acc[0], acc[1], acc[2], acc[3]);
    *(float4*)&red[w][lane * 8 + 4] = make_float4(acc[4], acc[5], acc[6], acc[7]);
    if ((lane & 7) == 0) lS[w][lane >> 3] = l;
    __syncthreads();

    const int d = t, k = d >> 6;
    float ls = 0.f, sum = 0.f;
    #pragma unroll
    for (int ww = 0; ww < KH; ww++) { ls += lS[ww][k]; sum += red[ww][d]; }
    Zaggb[(size_t)i * DD + d] = f2bf(sum / ls);
}

// ---------------------------------------------------------------------------
// K3: out = relu(H + 0.5 * (Zaggb . Bt2^T) - thr), f32 out. 64x64, BK=64.
// Block (0,0) additionally reduces the 112 orth partials -> out[NN*DD].
// ---------------------------------------------------------------------------
__global__ __launch_bounds__(256) void outgemm_mfma(const u16* __restrict__ Ab, const u16* __restrict__ Btb,
                                                    const float* __restrict__ H, const float* __restrict__ thr,
                                                    const float* __restrict__ lossP,
                                                    float* __restrict__ out) {
    __shared__ short As[64][72];
    __shared__ short Bs[64][72];
    const int t = threadIdx.x;
    const int i0 = blockIdx.x * 64, n0 = blockIdx.y * 64;
    if (i0 == 0 && n0 == 0 && t < 64) {
        float v = lossP[t] + ((t + 64 < 112) ? lossP[t + 64] : 0.f);
        #pragma unroll
        for (int off = 32; off; off >>= 1) v += __shfl_down(v, off, 64);
        if (t == 0) out[(size_t)NN * DD] = v;
    }
    const int w = t >> 6, lane = t & 63;
    const int lm = lane & 15, lg = lane >> 4;
    f32x4 acc[4] = {};
    for (int kc = 0; kc < DD; kc += 64) {
        #pragma unroll
        for (int s = 0; s < 2; s++) {
            int c = t + 256 * s; int row = c >> 3, g = c & 7;
            *(short8*)&As[row][g * 8] = *(const short8*)(Ab  + (size_t)(i0 + row) * DD + kc + g * 8);
            *(short8*)&Bs[row][g * 8] = *(const short8*)(Btb + (size_t)(n0 + row) * DD + kc + g * 8);
        }
        __syncthreads();
        #pragma unroll
        for (int ks = 0; ks < 64; ks += 32) {
            short8 af = *(const short8*)&As[w * 16 + lm][ks + lg * 8];
            #pragma unroll
            for (int b = 0; b < 4; b++) {
                short8 bfr = *(const short8*)&Bs[b * 16 + lm][ks + lg * 8];
                acc[b] = __builtin_amdgcn_mfma_f32_16x16x32_bf16(af, bfr, acc[b], 0, 0, 0);
            }
        }
        __syncthreads();
    }
    #pragma unroll
    for (int b = 0; b < 4; b++) {
        const int col = n0 + b * 16 + lm;
        const float th = thr[col];
        #pragma unroll
        for (int q = 0; q < 4; q++) {
            int row = i0 + w * 16 + lg * 4 + q;
            float h = H[(size_t)row * DD + col];
            out[(size_t)row * DD + col] = fmaxf(h + 0.5f * acc[b][q] - th, 0.f);
        }
    }
}

// ---------------------------------------------------------------------------
extern "C" void kernel_launch(void* const* d_in, const int* in_sizes, int n_in,
                              void* d_out, int out_size, void* d_ws, size_t ws_size,
                              hipStream_t stream) {
    const float* H   = (const float*)d_in[0];
    const float* adj = (const float*)d_in[1];
    const float* U   = (const float*)d_in[2];
    const float* thr = (const float*)d_in[3];
    float* out = (float*)d_out;

    char* ws = (char*)d_ws;
    float* lossP = (float*)ws;                                         // 112 floats (448 B)
    u16*   Hb    = (u16*)(ws + 1024);                                  // 4 MB
    u16*   Zb    = (u16*)(ws + 1024 + 4u * 1024 * 1024);               // 4 MB
    u16*   Zaggb = (u16*)(ws + 1024 + 8u * 1024 * 1024);               // 4 MB
    u16*   Bt1   = (u16*)(ws + 1024 + 12u * 1024 * 1024);              // 512 KB
    u16*   Bt2   = (u16*)(ws + 1024 + 12u * 1024 * 1024 + 512u * 1024);// 512 KB
    int*   nlist = (int*)(ws + 1024 + 13u * 1024 * 1024);              // 2 MB
    int*   cnt   = (int*)(ws + 1024 + 15u * 1024 * 1024 + 512u * 1024);// 16 KB

    prep_scan<<<3248, 256, 0, stream>>>(H, U, adj, Hb, Bt1, Bt2, nlist, cnt, lossP);
    zgemm_mfma<<<dim3(64, 8), 256, 0, stream>>>(Hb, Bt1, Zb);
    attn11<<<NN, 512, 0, stream>>>(Zb, nlist, cnt, Zaggb);
    outgemm_mfma<<<dim3(64, 8), 256, 0, stream>>>(Zaggb, Bt2, H, thr, lossP, out);
}